// Round 9
// baseline (276.506 us; speedup 1.0000x reference)
//
#include <hip/hip_runtime.h>

typedef __bf16 bf16;
typedef __bf16 bf16x4 __attribute__((ext_vector_type(4)));
typedef __bf16 bf16x8 __attribute__((ext_vector_type(8)));
typedef float f32x4 __attribute__((ext_vector_type(4)));

#define SEQ 4096
#define EMB 1024

#define MODE_BF16 0   // bf16 out (projections)
#define MODE_EXP  1   // bf16 out = exp(acc/32) + rowsum atomics (scores -> E)
#define MODE_ATOM 2   // fp32 atomicAdd into out (split-K PV)

// async global->LDS, 16B per lane; LDS dest = wave-uniform base + lane*16 (m97/m104)
__device__ __forceinline__ void async_copy16(void* lds, const void* g) {
    __builtin_amdgcn_global_load_lds(
        (const __attribute__((address_space(1))) unsigned int*)g,
        (__attribute__((address_space(3))) unsigned int*)lds,
        16, 0, 0);
}

// One prep kernel: fp32->bf16 of x, W_Q|W_K (stacked), W_V, plus zero-fill of
// out (atomic PV target) and rowsum. Segmented flat index, 4 elems/thread.
__global__ __launch_bounds__(256) void prep_all(const float* __restrict__ x,
                                                const float* __restrict__ wq,
                                                const float* __restrict__ wk,
                                                const float* __restrict__ wv,
                                                bf16* __restrict__ xb,
                                                bf16* __restrict__ wqk,
                                                bf16* __restrict__ wvb,
                                                float* __restrict__ out,
                                                float* __restrict__ rowsum)
{
    const int u = blockIdx.x * 256 + threadIdx.x;
    const float* src;
    bf16* dst;
    int off;
    if (u < 1048576)      { src = x;  dst = xb;               off = u; }
    else if (u < 1310720) { src = wq; dst = wqk;              off = u - 1048576; }
    else if (u < 1572864) { src = wk; dst = wqk + EMB * EMB;  off = u - 1310720; }
    else if (u < 1835008) { src = wv; dst = wvb;              off = u - 1572864; }
    else if (u < 2883584) {
        *(float4*)(out + (size_t)(u - 1835008) * 4) = float4{0.f, 0.f, 0.f, 0.f};
        return;
    } else {              // u < 2884608
        *(float4*)(rowsum + (size_t)(u - 2883584) * 4) = float4{0.f, 0.f, 0.f, 0.f};
        return;
    }
    float4 f = *(const float4*)(src + (size_t)off * 4);
    bf16x4 v = { (bf16)f.x, (bf16)f.y, (bf16)f.z, (bf16)f.w };
    *(bf16x4*)(dst + (size_t)off * 4) = v;
}

// C[m][n] = sum_k A[m][k] * B[n][k]  ("B^T" GEMM, both K-contiguous)
// grid = (N/128, M/128, splitK); BK=64; 256 threads (4 waves, 2x2 of 4x4 MFMA).
// LDS: row stride 64 elems; logical 16B k-chunk l of row r stored at physical
// chunk (l+r)&7 (swizzle via per-lane *global* source permutation; glds dest
// must stay base+lane*16). Fragment reads land 2-way on banks = free (m136, R8: 4.19M->0).
template<int OUT_MODE>
__global__ __launch_bounds__(256) void gemm_bt(const bf16* __restrict__ A,
                                               const bf16* __restrict__ B,
                                               void* __restrict__ Cv,
                                               float* __restrict__ rowsum,
                                               int lda, int ldb, int ldc, int K)
{
    __shared__ __align__(16) bf16 As[128 * 64];   // 16 KB
    __shared__ __align__(16) bf16 Bs[128 * 64];   // 16 KB

    const int tid  = threadIdx.x;
    const int lane = tid & 63;
    const int wave = tid >> 6;
    const int m0 = blockIdx.y * 128;
    const int n0 = blockIdx.x * 128;
    const size_t koff = (size_t)blockIdx.z * K;

    const int srow = tid >> 3;                 // staging row 0..31 (+32*t)
    const int spc  = tid & 7;                  // physical chunk (fixed by glds)
    const int sl   = (spc - (srow & 7)) & 7;   // logical chunk this lane fetches

    const int wm = (wave & 1) << 6;
    const int wn = (wave >> 1) << 6;
    const int fr = lane & 15;                  // fragment row
    const int q  = lane >> 4;                  // k-quad

    f32x4 acc[4][4];
    for (int i = 0; i < 4; i++)
        for (int j = 0; j < 4; j++)
            acc[i][j] = {0.f, 0.f, 0.f, 0.f};

    const bf16* Ab = A + (size_t)(m0 + srow) * lda + koff + sl * 8;
    const bf16* Bb = B + (size_t)(n0 + srow) * ldb + koff + sl * 8;

    bf16* AsD = &As[srow * 64 + spc * 8];
    bf16* BsD = &Bs[srow * 64 + spc * 8];

    const int pc0 = ((q + fr) & 7) * 8;        // physical chunk, k-half 0
    const int pc1 = (((q + fr) & 7) ^ 4) * 8;  // k-half 1 (+4 mod 8 == xor 4)

    for (int k0 = 0; k0 < K; k0 += 64) {
        __syncthreads();
        for (int t = 0; t < 4; t++) {
            async_copy16(AsD + t * 2048, Ab + k0 + (size_t)(32 * t) * lda);
            async_copy16(BsD + t * 2048, Bb + k0 + (size_t)(32 * t) * ldb);
        }
        __syncthreads();

        bf16x8 af[4], bg[4];
        for (int i = 0; i < 4; i++)
            af[i] = *(const bf16x8*)&As[(wm + i * 16 + fr) * 64 + pc0];
        for (int j = 0; j < 4; j++)
            bg[j] = *(const bf16x8*)&Bs[(wn + j * 16 + fr) * 64 + pc0];
        for (int i = 0; i < 4; i++)
            for (int j = 0; j < 4; j++)
                acc[i][j] = __builtin_amdgcn_mfma_f32_16x16x32_bf16(af[i], bg[j], acc[i][j], 0, 0, 0);
        for (int i = 0; i < 4; i++)
            af[i] = *(const bf16x8*)&As[(wm + i * 16 + fr) * 64 + pc1];
        for (int j = 0; j < 4; j++)
            bg[j] = *(const bf16x8*)&Bs[(wn + j * 16 + fr) * 64 + pc1];
        for (int i = 0; i < 4; i++)
            for (int j = 0; j < 4; j++)
                acc[i][j] = __builtin_amdgcn_mfma_f32_16x16x32_bf16(af[i], bg[j], acc[i][j], 0, 0, 0);
    }

    // C/D layout (verified m89): col = lane&15, row = (lane>>4)*4 + reg
    const int cm = m0 + wm + (q << 2);
    const int cn = n0 + wn + fr;
    if (OUT_MODE == MODE_BF16) {
        bf16* C = (bf16*)Cv;
        for (int i = 0; i < 4; i++)
            for (int j = 0; j < 4; j++)
                for (int r = 0; r < 4; r++)
                    C[(size_t)(cm + i * 16 + r) * ldc + (cn + j * 16)] = (bf16)acc[i][j][r];
    } else if (OUT_MODE == MODE_EXP) {
        // shift-free softmax numerator (scores ~N(0,1): exp safe in fp32/bf16);
        // also accumulate per-row sums of exp into rowsum[] via atomics.
        bf16* C = (bf16*)Cv;
        float rs[4][4];
        for (int i = 0; i < 4; i++)
            for (int r = 0; r < 4; r++) rs[i][r] = 0.f;
        for (int i = 0; i < 4; i++)
            for (int j = 0; j < 4; j++)
                for (int r = 0; r < 4; r++) {
                    float e = __expf(acc[i][j][r] * 0.03125f);
                    C[(size_t)(cm + i * 16 + r) * ldc + (cn + j * 16)] = (bf16)e;
                    rs[i][r] += e;
                }
        // butterfly over the 16 fr-lanes (masks<16 stay within the 16-group)
        for (int i = 0; i < 4; i++)
            for (int r = 0; r < 4; r++)
                for (int m = 1; m < 16; m <<= 1)
                    rs[i][r] += __shfl_xor(rs[i][r], m);
        if (fr == 0)
            for (int i = 0; i < 4; i++)
                for (int r = 0; r < 4; r++)
                    unsafeAtomicAdd(&rowsum[cm + i * 16 + r], rs[i][r]);
    } else {
        // split-K PV: accumulate into zero-filled out (HW fp32 atomic, no return)
        float* C = (float*)Cv;
        for (int i = 0; i < 4; i++)
            for (int j = 0; j < 4; j++)
                for (int r = 0; r < 4; r++)
                    unsafeAtomicAdd(&C[(size_t)(cm + i * 16 + r) * ldc + (cn + j * 16)],
                                    acc[i][j][r]);
    }
}

// out[m][*] *= 1/rowsum[m]; flat, 4 floats/thread
__global__ __launch_bounds__(256) void scale_rows(float* __restrict__ out,
                                                  const float* __restrict__ rowsum)
{
    const int gid = blockIdx.x * 256 + threadIdx.x;
    const int row = gid >> 8;                  // (gid*4)/1024
    const float inv = 1.f / rowsum[row];
    float4 v = *(const float4*)(out + (size_t)gid * 4);
    v.x *= inv; v.y *= inv; v.z *= inv; v.w *= inv;
    *(float4*)(out + (size_t)gid * 4) = v;
}

extern "C" void kernel_launch(void* const* d_in, const int* in_sizes, int n_in,
                              void* d_out, int out_size, void* d_ws, size_t ws_size,
                              hipStream_t stream)
{
    const float* x  = (const float*)d_in[0];   // (4096, 1024) fp32
    const float* wq = (const float*)d_in[1];   // (1024, 1024) fp32
    const float* wk = (const float*)d_in[2];
    const float* wv = (const float*)d_in[3];
    float* out = (float*)d_out;                // (4096, 1024) fp32

    char* ws = (char*)d_ws;
    const size_t MB = 1024 * 1024;
    bf16*  E   = (bf16*)(ws);                   // [0,32)   4096x4096 bf16
    bf16*  xb  = (bf16*)(ws + 32 * MB);         // [32,40)
    bf16*  wqk = (bf16*)(ws + 40 * MB);         // [40,44)  W_Q|W_K stacked (2048x1024)
    bf16*  wvb = (bf16*)(ws + 44 * MB);         // [44,46)
    float* rsm = (float*)(ws + 46 * MB);        // [46,46+16KB) rowsum[4096]
    bf16*  QK  = (bf16*)(ws + 64 * MB);         // [64,80)  4096x2048 (Q|K per row)
    bf16*  VT  = (bf16*)(ws + 80 * MB);         // [80,88)  1024x4096 = V^T

    dim3 blk(256);

    // 0. convert all inputs to bf16 + zero out/rowsum (one launch)
    prep_all<<<dim3(11268), blk, 0, stream>>>(x, wq, wk, wv, xb, wqk, wvb, out, rsm);

    // 1. [Q|K] = x @ [W_Q|W_K]^T   (M=4096, N=2048, K=1024)
    gemm_bt<MODE_BF16><<<dim3(16, 32), blk, 0, stream>>>(xb, wqk, QK, nullptr,
                                                         1024, 1024, 2048, 1024);
    // 2. V^T = W_V @ x^T           (M=1024, N=4096, K=1024)
    gemm_bt<MODE_BF16><<<dim3(32, 8), blk, 0, stream>>>(wvb, xb, VT, nullptr,
                                                        1024, 1024, 4096, 1024);
    // 3. E = exp((Q @ K^T)/32), rowsum += rowsums(E)   (M=N=4096, K=1024)
    gemm_bt<MODE_EXP><<<dim3(32, 32), blk, 0, stream>>>(QK, QK + 1024, E, rsm,
                                                        2048, 2048, 4096, 1024);
    // 4. out += E @ (V^T)^T        (M=4096, N=1024, K=4096 split 4x1024, atomic)
    gemm_bt<MODE_ATOM><<<dim3(8, 32, 4), blk, 0, stream>>>(E, VT, out, nullptr,
                                                           4096, 4096, 1024, 1024);
    // 5. out[m] /= rowsum[m]
    scale_rows<<<dim3(4096), blk, 0, stream>>>(out, rsm);
}

// Round 10
// 248.188 us; speedup vs baseline: 1.1141x; 1.1141x over previous
//
#include <hip/hip_runtime.h>

typedef __bf16 bf16;
typedef __bf16 bf16x4 __attribute__((ext_vector_type(4)));
typedef __bf16 bf16x8 __attribute__((ext_vector_type(8)));
typedef float f32x4 __attribute__((ext_vector_type(4)));

#define SEQ 4096
#define EMB 1024

#define MODE_BF16 0   // bf16 out (projections)
#define MODE_EXP  1   // bf16 out = exp(acc/32) + rowsum atomics (scores -> E)
#define MODE_PART 2   // fp32 partial stores, split-K via blockIdx.z (R9 atomics regressed)

// async global->LDS, 16B per lane; LDS dest = wave-uniform base + lane*16 (m97/m104)
__device__ __forceinline__ void async_copy16(void* lds, const void* g) {
    __builtin_amdgcn_global_load_lds(
        (const __attribute__((address_space(1))) unsigned int*)g,
        (__attribute__((address_space(3))) unsigned int*)lds,
        16, 0, 0);
}

// One prep kernel: fp32->bf16 of x, W_Q|W_K (stacked), W_V; zero rowsum.
__global__ __launch_bounds__(256) void prep_all(const float* __restrict__ x,
                                                const float* __restrict__ wq,
                                                const float* __restrict__ wk,
                                                const float* __restrict__ wv,
                                                bf16* __restrict__ xb,
                                                bf16* __restrict__ wqk,
                                                bf16* __restrict__ wvb,
                                                float* __restrict__ rowsum)
{
    const int u = blockIdx.x * 256 + threadIdx.x;
    const float* src;
    bf16* dst;
    int off;
    if (u < 1048576)      { src = x;  dst = xb;               off = u; }
    else if (u < 1310720) { src = wq; dst = wqk;              off = u - 1048576; }
    else if (u < 1572864) { src = wk; dst = wqk + EMB * EMB;  off = u - 1310720; }
    else if (u < 1835008) { src = wv; dst = wvb;              off = u - 1572864; }
    else {                // u < 1836032: zero rowsum[4096]
        *(float4*)(rowsum + (size_t)(u - 1835008) * 4) = float4{0.f, 0.f, 0.f, 0.f};
        return;
    }
    float4 f = *(const float4*)(src + (size_t)off * 4);
    bf16x4 v = { (bf16)f.x, (bf16)f.y, (bf16)f.z, (bf16)f.w };
    *(bf16x4*)(dst + (size_t)off * 4) = v;
}

// C[m][n] = sum_k A[m][k] * B[n][k]  ("B^T" GEMM, both K-contiguous)
// grid = (N/128, M/128, splitK); BK=64; 256 threads (4 waves, 2x2 of 4x4 MFMA).
// LDS: row stride 64 elems; logical 16B k-chunk l of row r stored at physical
// chunk (l+r)&7 (swizzle via per-lane *global* source permutation; glds dest
// must stay base+lane*16). Bank conflicts: 4.19M -> 0 (R8).
template<int OUT_MODE>
__global__ __launch_bounds__(256) void gemm_bt(const bf16* __restrict__ A,
                                               const bf16* __restrict__ B,
                                               void* __restrict__ Cv,
                                               float* __restrict__ aux,
                                               int lda, int ldb, int ldc, int K)
{
    __shared__ __align__(16) bf16 As[128 * 64];   // 16 KB
    __shared__ __align__(16) bf16 Bs[128 * 64];   // 16 KB

    const int tid  = threadIdx.x;
    const int lane = tid & 63;
    const int wave = tid >> 6;
    const int m0 = blockIdx.y * 128;
    const int n0 = blockIdx.x * 128;
    const size_t koff = (size_t)blockIdx.z * K;

    const int srow = tid >> 3;                 // staging row 0..31 (+32*t)
    const int spc  = tid & 7;                  // physical chunk (fixed by glds)
    const int sl   = (spc - (srow & 7)) & 7;   // logical chunk this lane fetches

    const int wm = (wave & 1) << 6;
    const int wn = (wave >> 1) << 6;
    const int fr = lane & 15;                  // fragment row
    const int q  = lane >> 4;                  // k-quad

    f32x4 acc[4][4];
    for (int i = 0; i < 4; i++)
        for (int j = 0; j < 4; j++)
            acc[i][j] = {0.f, 0.f, 0.f, 0.f};

    const bf16* Ab = A + (size_t)(m0 + srow) * lda + koff + sl * 8;
    const bf16* Bb = B + (size_t)(n0 + srow) * ldb + koff + sl * 8;

    bf16* AsD = &As[srow * 64 + spc * 8];
    bf16* BsD = &Bs[srow * 64 + spc * 8];

    const int pc0 = ((q + fr) & 7) * 8;        // physical chunk, k-half 0
    const int pc1 = (((q + fr) & 7) ^ 4) * 8;  // k-half 1 (+4 mod 8 == xor 4)

    for (int k0 = 0; k0 < K; k0 += 64) {
        __syncthreads();
        for (int t = 0; t < 4; t++) {
            async_copy16(AsD + t * 2048, Ab + k0 + (size_t)(32 * t) * lda);
            async_copy16(BsD + t * 2048, Bb + k0 + (size_t)(32 * t) * ldb);
        }
        __syncthreads();

        bf16x8 af[4], bg[4];
        for (int i = 0; i < 4; i++)
            af[i] = *(const bf16x8*)&As[(wm + i * 16 + fr) * 64 + pc0];
        for (int j = 0; j < 4; j++)
            bg[j] = *(const bf16x8*)&Bs[(wn + j * 16 + fr) * 64 + pc0];
        for (int i = 0; i < 4; i++)
            for (int j = 0; j < 4; j++)
                acc[i][j] = __builtin_amdgcn_mfma_f32_16x16x32_bf16(af[i], bg[j], acc[i][j], 0, 0, 0);
        for (int i = 0; i < 4; i++)
            af[i] = *(const bf16x8*)&As[(wm + i * 16 + fr) * 64 + pc1];
        for (int j = 0; j < 4; j++)
            bg[j] = *(const bf16x8*)&Bs[(wn + j * 16 + fr) * 64 + pc1];
        for (int i = 0; i < 4; i++)
            for (int j = 0; j < 4; j++)
                acc[i][j] = __builtin_amdgcn_mfma_f32_16x16x32_bf16(af[i], bg[j], acc[i][j], 0, 0, 0);
    }

    // C/D layout (verified m89): col = lane&15, row = (lane>>4)*4 + reg
    const int cm = m0 + wm + (q << 2);
    const int cn = n0 + wn + fr;
    if (OUT_MODE == MODE_BF16) {
        bf16* C = (bf16*)Cv;
        for (int i = 0; i < 4; i++)
            for (int j = 0; j < 4; j++)
                for (int r = 0; r < 4; r++)
                    C[(size_t)(cm + i * 16 + r) * ldc + (cn + j * 16)] = (bf16)acc[i][j][r];
    } else if (OUT_MODE == MODE_EXP) {
        // shift-free softmax numerator (scores ~N(0,1): exp safe in fp32/bf16);
        // per-row partial sums of exp -> rowsum[] atomics (32 adds/row total: cheap).
        bf16* C = (bf16*)Cv;
        float rs[4][4];
        for (int i = 0; i < 4; i++)
            for (int r = 0; r < 4; r++) rs[i][r] = 0.f;
        for (int i = 0; i < 4; i++)
            for (int j = 0; j < 4; j++)
                for (int r = 0; r < 4; r++) {
                    float e = __expf(acc[i][j][r] * 0.03125f);
                    C[(size_t)(cm + i * 16 + r) * ldc + (cn + j * 16)] = (bf16)e;
                    rs[i][r] += e;
                }
        for (int i = 0; i < 4; i++)
            for (int r = 0; r < 4; r++)
                for (int m = 1; m < 16; m <<= 1)
                    rs[i][r] += __shfl_xor(rs[i][r], m);
        if (fr == 0)
            for (int i = 0; i < 4; i++)
                for (int r = 0; r < 4; r++)
                    unsafeAtomicAdd(&aux[cm + i * 16 + r], rs[i][r]);
    } else {
        // split-K PV: z=0 -> Cv (d_out), z>=1 -> partial buffer (plain stores)
        float* C = (blockIdx.z == 0) ? (float*)Cv
                                     : aux + (size_t)(blockIdx.z - 1) * SEQ * 1024;
        for (int i = 0; i < 4; i++)
            for (int j = 0; j < 4; j++)
                for (int r = 0; r < 4; r++)
                    C[(size_t)(cm + i * 16 + r) * ldc + (cn + j * 16)] = acc[i][j][r];
    }
}

// one block per row m (256 threads x 4 floats = 1024 cols):
// out[m] = (out[m] + p1[m] + p2[m] + p3[m]) / rowsum[m]
__global__ __launch_bounds__(256) void reduce_norm(float* __restrict__ out,
                                                   const float* __restrict__ p1,
                                                   const float* __restrict__ p2,
                                                   const float* __restrict__ p3,
                                                   const float* __restrict__ rowsum)
{
    const int m = blockIdx.x;
    const float inv = 1.f / rowsum[m];
    const size_t off = (size_t)m * 1024 + threadIdx.x * 4;
    float4 a = *(const float4*)(out + off);
    float4 b = *(const float4*)(p1 + off);
    float4 c = *(const float4*)(p2 + off);
    float4 d = *(const float4*)(p3 + off);
    float4 o;
    o.x = (a.x + b.x + c.x + d.x) * inv;
    o.y = (a.y + b.y + c.y + d.y) * inv;
    o.z = (a.z + b.z + c.z + d.z) * inv;
    o.w = (a.w + b.w + c.w + d.w) * inv;
    *(float4*)(out + off) = o;
}

extern "C" void kernel_launch(void* const* d_in, const int* in_sizes, int n_in,
                              void* d_out, int out_size, void* d_ws, size_t ws_size,
                              hipStream_t stream)
{
    const float* x  = (const float*)d_in[0];   // (4096, 1024) fp32
    const float* wq = (const float*)d_in[1];   // (1024, 1024) fp32
    const float* wk = (const float*)d_in[2];
    const float* wv = (const float*)d_in[3];
    float* out = (float*)d_out;                // (4096, 1024) fp32

    char* ws = (char*)d_ws;
    const size_t MB = 1024 * 1024;
    // lifetimes: xb/wqk/wvb (phases 0-2) die before p1 written (phase 4);
    // QK (1-3) dies before p3 (phase 4). E, VT, rsm live through phase 5.
    bf16*  E   = (bf16*)(ws);                   // [0,32)   4096x4096 bf16
    float* p1  = (float*)(ws + 32 * MB);        // [32,48)  PV partial z=1
    float* p2  = (float*)(ws + 48 * MB);        // [48,64)  PV partial z=2
    float* p3  = (float*)(ws + 64 * MB);        // [64,80)  PV partial z=3
    bf16*  xb  = (bf16*)(ws + 32 * MB);         // [32,40)  (dead < phase 4)
    bf16*  wqk = (bf16*)(ws + 40 * MB);         // [40,44)  W_Q|W_K (2048x1024)
    bf16*  wvb = (bf16*)(ws + 44 * MB);         // [44,46)
    bf16*  QK  = (bf16*)(ws + 64 * MB);         // [64,80)  4096x2048 (Q|K per row)
    bf16*  VT  = (bf16*)(ws + 80 * MB);         // [80,88)  1024x4096 = V^T
    float* rsm = (float*)(ws + 88 * MB);        // [88,88+16KB) rowsum[4096]

    dim3 blk(256);

    // 0. convert inputs to bf16 + zero rowsum (one launch)
    prep_all<<<dim3(7172), blk, 0, stream>>>(x, wq, wk, wv, xb, wqk, wvb, rsm);

    // 1. [Q|K] = x @ [W_Q|W_K]^T   (M=4096, N=2048, K=1024)
    gemm_bt<MODE_BF16><<<dim3(16, 32), blk, 0, stream>>>(xb, wqk, QK, nullptr,
                                                         1024, 1024, 2048, 1024);
    // 2. V^T = W_V @ x^T           (M=1024, N=4096, K=1024)
    gemm_bt<MODE_BF16><<<dim3(32, 8), blk, 0, stream>>>(wvb, xb, VT, nullptr,
                                                        1024, 1024, 4096, 1024);
    // 3. E = exp((Q @ K^T)/32), rowsum += rowsums(E)   (M=N=4096, K=1024)
    gemm_bt<MODE_EXP><<<dim3(32, 32), blk, 0, stream>>>(QK, QK + 1024, E, rsm,
                                                        2048, 2048, 4096, 1024);
    // 4. partials = E @ (V^T)^T    (M=4096, N=1024, K=4096 split 4x1024, stores)
    gemm_bt<MODE_PART><<<dim3(8, 32, 4), blk, 0, stream>>>(E, VT, out, p1,
                                                           4096, 4096, 1024, 1024);
    // 5. out[m] = (out + p1 + p2 + p3)[m] / rowsum[m]
    reduce_norm<<<dim3(4096), blk, 0, stream>>>(out, p1, p2, p3, rsm);
}

// Round 11
// 215.877 us; speedup vs baseline: 1.2809x; 1.1497x over previous
//
#include <hip/hip_runtime.h>

typedef __bf16 bf16;
typedef __bf16 bf16x4 __attribute__((ext_vector_type(4)));
typedef __bf16 bf16x8 __attribute__((ext_vector_type(8)));
typedef float f32x4 __attribute__((ext_vector_type(4)));

#define SEQ 4096
#define EMB 1024

// async global->LDS, 16B per lane; LDS dest = wave-uniform base + lane*16 (m97/m104)
__device__ __forceinline__ void async_copy16(void* lds, const void* g) {
    __builtin_amdgcn_global_load_lds(
        (const __attribute__((address_space(1))) unsigned int*)g,
        (__attribute__((address_space(3))) unsigned int*)lds,
        16, 0, 0);
}

// One prep kernel: fp32->bf16 of x, W_Q|W_K (stacked), W_V; zero rowsum.
__global__ __launch_bounds__(256) void prep_all(const float* __restrict__ x,
                                                const float* __restrict__ wq,
                                                const float* __restrict__ wk,
                                                const float* __restrict__ wv,
                                                bf16* __restrict__ xb,
                                                bf16* __restrict__ wqk,
                                                bf16* __restrict__ wvb,
                                                float* __restrict__ rowsum)
{
    const int u = blockIdx.x * 256 + threadIdx.x;
    const float* src;
    bf16* dst;
    int off;
    if (u < 1048576)      { src = x;  dst = xb;               off = u; }
    else if (u < 1310720) { src = wq; dst = wqk;              off = u - 1048576; }
    else if (u < 1572864) { src = wk; dst = wqk + EMB * EMB;  off = u - 1310720; }
    else if (u < 1835008) { src = wv; dst = wvb;              off = u - 1572864; }
    else {                // u < 1836032: zero rowsum[4096]
        *(float4*)(rowsum + (size_t)(u - 1835008) * 4) = float4{0.f, 0.f, 0.f, 0.f};
        return;
    }
    float4 f = *(const float4*)(src + (size_t)off * 4);
    bf16x4 v = { (bf16)f.x, (bf16)f.y, (bf16)f.z, (bf16)f.w };
    *(bf16x4*)(dst + (size_t)off * 4) = v;
}

// Shared GEMM core: C[m][n] = sum_k A[m][k]*B[n][k], 128x128 tile, BK=64,
// 256 threads (4 waves 2x2 of 4x4 16x16x32 MFMA). LDS row stride 64 elems,
// k-chunk swizzle (l+r)&7 via per-lane global-source permutation (R8: conflicts 0).
// RSUM: accumulate per-row sums of A-fragments (A-layout: lane fr = row, so
// Sum_j af[i][j] is a per-row partial; q-lanes cover disjoint k-chunks).
template<bool RSUM>
__device__ __forceinline__ void gemm_core(const bf16* __restrict__ A,
                                          const bf16* __restrict__ B,
                                          int lda, int ldb, int K, long koff,
                                          int m0, int n0,
                                          bf16* __restrict__ As, bf16* __restrict__ Bs,
                                          f32x4 (&acc)[4][4], float (&rsum)[4],
                                          bool rs_active)
{
    const int tid  = threadIdx.x;
    const int lane = tid & 63;
    const int wave = tid >> 6;
    const int srow = tid >> 3;                 // staging row 0..31 (+32*t)
    const int spc  = tid & 7;                  // physical chunk (fixed by glds)
    const int sl   = (spc - (srow & 7)) & 7;   // logical chunk this lane fetches
    const int wm = (wave & 1) << 6;
    const int wn = (wave >> 1) << 6;
    const int fr = lane & 15;
    const int q  = lane >> 4;

    for (int i = 0; i < 4; i++)
        for (int j = 0; j < 4; j++)
            acc[i][j] = {0.f, 0.f, 0.f, 0.f};
    if (RSUM)
        for (int i = 0; i < 4; i++) rsum[i] = 0.f;

    const bf16* Ab = A + (size_t)(m0 + srow) * lda + koff + sl * 8;
    const bf16* Bb = B + (size_t)(n0 + srow) * ldb + koff + sl * 8;
    bf16* AsD = &As[srow * 64 + spc * 8];
    bf16* BsD = &Bs[srow * 64 + spc * 8];

    const int pc0 = ((q + fr) & 7) * 8;   // physical chunk byte/elem offset, k-half 0
    const int pc1 = pc0 ^ 32;             // k-half 1: (+4 mod 8) == xor 4 (x8 elems)

    for (int k0 = 0; k0 < K; k0 += 64) {
        __syncthreads();
        for (int t = 0; t < 4; t++) {
            async_copy16(AsD + t * 2048, Ab + k0 + (size_t)(32 * t) * lda);
            async_copy16(BsD + t * 2048, Bb + k0 + (size_t)(32 * t) * ldb);
        }
        __syncthreads();

        bf16x8 af[4], bg[4];
        for (int i = 0; i < 4; i++)
            af[i] = *(const bf16x8*)&As[(wm + i * 16 + fr) * 64 + pc0];
        for (int j = 0; j < 4; j++)
            bg[j] = *(const bf16x8*)&Bs[(wn + j * 16 + fr) * 64 + pc0];
        if (RSUM && rs_active)
            for (int i = 0; i < 4; i++)
                for (int e = 0; e < 8; e++) rsum[i] += (float)af[i][e];
        for (int i = 0; i < 4; i++)
            for (int j = 0; j < 4; j++)
                acc[i][j] = __builtin_amdgcn_mfma_f32_16x16x32_bf16(af[i], bg[j], acc[i][j], 0, 0, 0);

        for (int i = 0; i < 4; i++)
            af[i] = *(const bf16x8*)&As[(wm + i * 16 + fr) * 64 + pc1];
        for (int j = 0; j < 4; j++)
            bg[j] = *(const bf16x8*)&Bs[(wn + j * 16 + fr) * 64 + pc1];
        if (RSUM && rs_active)
            for (int i = 0; i < 4; i++)
                for (int e = 0; e < 8; e++) rsum[i] += (float)af[i][e];
        for (int i = 0; i < 4; i++)
            for (int j = 0; j < 4; j++)
                acc[i][j] = __builtin_amdgcn_mfma_f32_16x16x32_bf16(af[i], bg[j], acc[i][j], 0, 0, 0);
    }
}

// Merged projections, one launch. Grid (32, 24):
//  y<16 : [Q|K] = xb @ wqk^T  (m-tile = x, n-tile = y)       -> QK (ldc 2048)
//  y>=16: V^T   = wvb @ xb^T  (m-tile = x&7, n = x>>3 | (y-16)<<2) -> VT (ldc 4096)
// n is the slow grid dim so same-A blocks co-locate per XCD (linear stride 32 % 8 == 0).
__global__ __launch_bounds__(256) void gemm_proj(const bf16* __restrict__ xb,
                                                 const bf16* __restrict__ wqk,
                                                 const bf16* __restrict__ wvb,
                                                 bf16* __restrict__ QK,
                                                 bf16* __restrict__ VT)
{
    __shared__ __align__(16) bf16 As[128 * 64];
    __shared__ __align__(16) bf16 Bs[128 * 64];

    const bf16 *A, *B;
    bf16* C;
    int ldc, m0, n0;
    if (blockIdx.y < 16) {
        A = xb; B = wqk; C = QK; ldc = 2048;
        m0 = blockIdx.x * 128; n0 = blockIdx.y * 128;
    } else {
        A = wvb; B = xb; C = VT; ldc = 4096;
        m0 = (blockIdx.x & 7) * 128;
        n0 = ((blockIdx.x >> 3) + ((blockIdx.y - 16) << 2)) * 128;
    }

    f32x4 acc[4][4];
    float rs[4];
    gemm_core<false>(A, B, 1024, 1024, 1024, 0, m0, n0, As, Bs, acc, rs, false);

    const int lane = threadIdx.x & 63;
    const int wave = threadIdx.x >> 6;
    const int cm = m0 + ((wave & 1) << 6) + ((lane >> 4) << 2);
    const int cn = n0 + ((wave >> 1) << 6) + (lane & 15);
    for (int i = 0; i < 4; i++)
        for (int j = 0; j < 4; j++)
            for (int r = 0; r < 4; r++)
                C[(size_t)(cm + i * 16 + r) * ldc + (cn + j * 16)] = (bf16)acc[i][j][r];
}

// E = exp((Q @ K^T)/32), bf16. Grid (32 m, 32 n); shift-free softmax numerator
// (scores ~N(0,1): exp safe in fp32/bf16; softmax is shift-invariant).
__global__ __launch_bounds__(256) void gemm_exp(const bf16* __restrict__ QK,
                                                bf16* __restrict__ E)
{
    __shared__ __align__(16) bf16 As[128 * 64];
    __shared__ __align__(16) bf16 Bs[128 * 64];

    const int m0 = blockIdx.x * 128;
    const int n0 = blockIdx.y * 128;
    f32x4 acc[4][4];
    float rs[4];
    gemm_core<false>(QK, QK + 1024, 2048, 2048, 1024, 0, m0, n0, As, Bs, acc, rs, false);

    const int lane = threadIdx.x & 63;
    const int wave = threadIdx.x >> 6;
    const int cm = m0 + ((wave & 1) << 6) + ((lane >> 4) << 2);
    const int cn = n0 + ((wave >> 1) << 6) + (lane & 15);
    for (int i = 0; i < 4; i++)
        for (int j = 0; j < 4; j++)
            for (int r = 0; r < 4; r++)
                E[(size_t)(cm + i * 16 + r) * 4096 + (cn + j * 16)] =
                    (bf16)__expf(acc[i][j][r] * 0.03125f);
}

// PV partials + rowsum-from-A-frags. Grid (32 m, 8 n, 4 z); K=1024/slice.
// z=0 stores to out, z>=1 to p1+(z-1)*4M. Blocks with n-tile==0, waves 0-1
// accumulate rowsum partials from the E fragments they already load (free);
// 2-stage q-butterfly + 4 atomics per lane 0..15.
__global__ __launch_bounds__(256) void gemm_pv(const bf16* __restrict__ E,
                                               const bf16* __restrict__ VT,
                                               float* __restrict__ out,
                                               float* __restrict__ p1,
                                               float* __restrict__ rowsum)
{
    __shared__ __align__(16) bf16 As[128 * 64];
    __shared__ __align__(16) bf16 Bs[128 * 64];

    const int m0 = blockIdx.x * 128;
    const int n0 = blockIdx.y * 128;
    const long koff = (long)blockIdx.z * 1024;
    const bool rs_active = (blockIdx.y == 0) && (threadIdx.x < 128);  // waves 0,1

    f32x4 acc[4][4];
    float rs[4];
    gemm_core<true>(E, VT, 4096, 4096, 1024, koff, m0, n0, As, Bs, acc, rs, rs_active);

    const int lane = threadIdx.x & 63;
    const int wave = threadIdx.x >> 6;
    if (rs_active) {
        for (int i = 0; i < 4; i++) {
            rs[i] += __shfl_xor(rs[i], 16);
            rs[i] += __shfl_xor(rs[i], 32);
        }
        if (lane < 16) {
            const int wm = (wave & 1) << 6;
            for (int i = 0; i < 4; i++)
                unsafeAtomicAdd(&rowsum[m0 + wm + i * 16 + lane], rs[i]);
        }
    }

    float* C = (blockIdx.z == 0) ? out : p1 + (size_t)(blockIdx.z - 1) * SEQ * 1024;
    const int cm = m0 + ((wave & 1) << 6) + ((lane >> 4) << 2);
    const int cn = n0 + ((wave >> 1) << 6) + (lane & 15);
    for (int i = 0; i < 4; i++)
        for (int j = 0; j < 4; j++)
            for (int r = 0; r < 4; r++)
                C[(size_t)(cm + i * 16 + r) * 1024 + (cn + j * 16)] = acc[i][j][r];
}

// one block per row m: out[m] = (out[m] + p1[m] + p2[m] + p3[m]) / rowsum[m]
__global__ __launch_bounds__(256) void reduce_norm(float* __restrict__ out,
                                                   const float* __restrict__ p1,
                                                   const float* __restrict__ p2,
                                                   const float* __restrict__ p3,
                                                   const float* __restrict__ rowsum)
{
    const int m = blockIdx.x;
    const float inv = 1.f / rowsum[m];
    const size_t off = (size_t)m * 1024 + threadIdx.x * 4;
    float4 a = *(const float4*)(out + off);
    float4 b = *(const float4*)(p1 + off);
    float4 c = *(const float4*)(p2 + off);
    float4 d = *(const float4*)(p3 + off);
    float4 o;
    o.x = (a.x + b.x + c.x + d.x) * inv;
    o.y = (a.y + b.y + c.y + d.y) * inv;
    o.z = (a.z + b.z + c.z + d.z) * inv;
    o.w = (a.w + b.w + c.w + d.w) * inv;
    *(float4*)(out + off) = o;
}

extern "C" void kernel_launch(void* const* d_in, const int* in_sizes, int n_in,
                              void* d_out, int out_size, void* d_ws, size_t ws_size,
                              hipStream_t stream)
{
    const float* x  = (const float*)d_in[0];   // (4096, 1024) fp32
    const float* wq = (const float*)d_in[1];   // (1024, 1024) fp32
    const float* wk = (const float*)d_in[2];
    const float* wv = (const float*)d_in[3];
    float* out = (float*)d_out;                // (4096, 1024) fp32

    char* ws = (char*)d_ws;
    const size_t MB = 1024 * 1024;
    bf16*  E   = (bf16*)(ws);                   // [0,32)   4096x4096 bf16
    float* p1  = (float*)(ws + 32 * MB);        // [32,48)  PV partial z=1
    float* p2  = (float*)(ws + 48 * MB);        // [48,64)  PV partial z=2
    float* p3  = (float*)(ws + 64 * MB);        // [64,80)  PV partial z=3
    bf16*  xb  = (bf16*)(ws + 32 * MB);         // [32,40)  (dead before p1 written)
    bf16*  wqk = (bf16*)(ws + 40 * MB);         // [40,44)  W_Q|W_K (2048x1024)
    bf16*  wvb = (bf16*)(ws + 44 * MB);         // [44,46)
    bf16*  QK  = (bf16*)(ws + 64 * MB);         // [64,80)  4096x2048 (dead before p3)
    bf16*  VT  = (bf16*)(ws + 80 * MB);         // [80,88)  1024x4096 = V^T
    float* rsm = (float*)(ws + 88 * MB);        // [88,88+16KB) rowsum (proven mapped R10)

    dim3 blk(256);

    // 0. convert inputs to bf16 + zero rowsum
    prep_all<<<dim3(7172), blk, 0, stream>>>(x, wq, wk, wv, xb, wqk, wvb, rsm);
    // 1. merged projections: QK (512 blocks) + VT (256 blocks)
    gemm_proj<<<dim3(32, 24), blk, 0, stream>>>(xb, wqk, wvb, QK, VT);
    // 2. E = exp((Q @ K^T)/32)
    gemm_exp<<<dim3(32, 32), blk, 0, stream>>>(QK, E);
    // 3. PV partials (split-K 4) + rowsum
    gemm_pv<<<dim3(32, 8, 4), blk, 0, stream>>>(E, VT, out, p1, rsm);
    // 4. out[m] = (out + p1 + p2 + p3)[m] / rowsum[m]
    reduce_norm<<<dim3(4096), blk, 0, stream>>>(out, p1, p2, p3, rsm);
}